// Round 10
// baseline (233.911 us; speedup 1.0000x reference)
//
#include <hip/hip_runtime.h>
#include <hip/hip_bf16.h>

typedef __attribute__((ext_vector_type(8))) __bf16 bf16x8;
typedef __attribute__((ext_vector_type(8))) short short8;
typedef __attribute__((ext_vector_type(4))) float f32x4;
typedef __attribute__((ext_vector_type(4))) short sh4;

typedef __attribute__((address_space(1))) void GVoid;
typedef __attribute__((address_space(3))) void LVoid;

#define NEGBIG (-1e30f)
#define SCL 0.18033688011112042f   // 0.125 * log2(e): folded into Q at GEMM1 epilogue

constexpr int TT = 2048, CC = 1024, HH = 16, DD = 64, C3 = 3072;

__device__ __forceinline__ unsigned short f2bf(float f) {   // RNE
  unsigned int i = __float_as_uint(f);
  return (unsigned short)((i + 0x7FFFu + ((i >> 16) & 1u)) >> 16);
}
__device__ __forceinline__ unsigned short f2bf_tr(float f) {  // truncate (P only)
  return (unsigned short)(__float_as_uint(f) >> 16);
}
__device__ __forceinline__ void async16(const void* g, void* l) {
  __builtin_amdgcn_global_load_lds((GVoid*)g, (LVoid*)l, 16, 0, 0);
}

// ---------- pre-pass: fp32 -> bf16 elementwise convert ----------
__global__ __launch_bounds__(256) void cvt_bf16(
    const float* __restrict__ in, unsigned short* __restrict__ out, int n8)
{
  const int i = blockIdx.x * 256 + threadIdx.x;
  if (i >= n8) return;
  const float* p = in + (size_t)i * 8;
  f32x4 a = *(const f32x4*)p, b = *(const f32x4*)(p + 4);
  sh4 r0, r1;
  ((unsigned short*)&r0)[0] = f2bf(a[0]); ((unsigned short*)&r0)[1] = f2bf(a[1]);
  ((unsigned short*)&r0)[2] = f2bf(a[2]); ((unsigned short*)&r0)[3] = f2bf(a[3]);
  ((unsigned short*)&r1)[0] = f2bf(b[0]); ((unsigned short*)&r1)[1] = f2bf(b[1]);
  ((unsigned short*)&r1)[2] = f2bf(b[2]); ((unsigned short*)&r1)[3] = f2bf(b[3]);
  *(sh4*)(out + (size_t)i * 8) = r0;
  *(sh4*)(out + (size_t)i * 8 + 4) = r1;
}

// ---------- pre-pass: transpose + convert: fp32 in[R][Cd] -> bf16 out[Cd][R] ----------
__global__ __launch_bounds__(256) void transpose_cvt(
    const float* __restrict__ in, unsigned short* __restrict__ out, int R, int Cd)
{
  __shared__ __align__(16) unsigned short tile[64 * 72];
  const int r0 = blockIdx.y * 64, c0 = blockIdx.x * 64;
  const int tid = threadIdx.x;
#pragma unroll
  for (int r = 0; r < 2; ++r) {
    const int elem = r * 2048 + tid * 8;
    const int ii = elem >> 6, jj = elem & 63;
    const float* p = in + (size_t)(r0 + ii) * Cd + c0 + jj;
    f32x4 a = *(const f32x4*)p, b = *(const f32x4*)(p + 4);
    short8 v;
    ((unsigned short*)&v)[0] = f2bf(a[0]); ((unsigned short*)&v)[1] = f2bf(a[1]);
    ((unsigned short*)&v)[2] = f2bf(a[2]); ((unsigned short*)&v)[3] = f2bf(a[3]);
    ((unsigned short*)&v)[4] = f2bf(b[0]); ((unsigned short*)&v)[5] = f2bf(b[1]);
    ((unsigned short*)&v)[6] = f2bf(b[2]); ((unsigned short*)&v)[7] = f2bf(b[3]);
    *(short8*)&tile[ii * 72 + jj] = v;
  }
  __syncthreads();
#pragma unroll
  for (int r = 0; r < 2; ++r) {
    const int elem = r * 2048 + tid * 8;
    const int jj = elem >> 6, ii0 = elem & 63;
    short8 v;
#pragma unroll
    for (int e = 0; e < 8; ++e) ((unsigned short*)&v)[e] = tile[(ii0 + e) * 72 + jj];
    *(short8*)&out[(size_t)(c0 + jj) * R + r0 + ii0] = v;
  }
}

// ---------------- GEMM (m97 structure, unchanged from R9) ----------------
template <int MODE>
__global__ __launch_bounds__(256) void gemm_bt(
    const unsigned short* __restrict__ A,
    const unsigned short* __restrict__ Bt,
    const float* __restrict__ bias,
    void* __restrict__ Cp, unsigned short* __restrict__ Vt,
    int M, int N, int K, int lda)
{
  __shared__ __align__(16) unsigned short sA[128 * 32];
  __shared__ __align__(16) unsigned short sB[128 * 32];
  const int tid = threadIdx.x;
  const int w = tid >> 6, l = tid & 63, ln = l & 15, quad = l >> 4;
  const int wm = w >> 1, wn = w & 1;
  const int m0 = blockIdx.y * 128, n0 = blockIdx.x * 128;
  f32x4 acc[4][4] = {};

  for (int k0 = 0; k0 < K; k0 += 32) {
    __syncthreads();
#pragma unroll
    for (int r = 0; r < 2; ++r) {
      const int elem = r * 2048 + tid * 8;
      const int ar = elem >> 5, ac = elem & 31;
      async16(A  + (size_t)(m0 + ar) * lda + k0 + ac, sA + r * 2048 + w * 512);
      async16(Bt + (size_t)(n0 + ar) * K   + k0 + ac, sB + r * 2048 + w * 512);
    }
    __syncthreads();

    bf16x8 af[4], bfr[4];
#pragma unroll
    for (int i = 0; i < 4; i++)
      af[i] = *(const bf16x8*)&sA[(wm * 64 + i * 16 + ln) * 32 + quad * 8];
#pragma unroll
    for (int j = 0; j < 4; j++)
      bfr[j] = *(const bf16x8*)&sB[(wn * 64 + j * 16 + ln) * 32 + quad * 8];
#pragma unroll
    for (int i = 0; i < 4; i++)
#pragma unroll
      for (int j = 0; j < 4; j++)
        acc[i][j] = __builtin_amdgcn_mfma_f32_16x16x32_bf16(af[i], bfr[j], acc[i][j], 0, 0, 0);
  }

  float bj[4];
#pragma unroll
  for (int j = 0; j < 4; j++) bj[j] = bias[n0 + wn * 64 + j * 16 + ln];

#pragma unroll
  for (int i = 0; i < 4; i++)
#pragma unroll
    for (int g = 0; g < 4; ++g) {
      const int gm = m0 + wm * 64 + i * 16 + quad * 4 + g;
#pragma unroll
      for (int j = 0; j < 4; j++) {
        const int gn = n0 + wn * 64 + j * 16 + ln;
        float v = acc[i][j][g] + bj[j];
        if (MODE == 0) {
          if (gn < 2048) {
            if (gn < 1024) v *= SCL;       // fold softmax scale into Q
            ((unsigned short*)Cp)[(size_t)gm * 2048 + gn] = f2bf(v);
          } else {
            const int hh = (gn >> 6) & 15, dd = gn & 63;
            const int bb = gm >> 11, t = gm & 2047;
            Vt[((size_t)((bb * HH + hh) * DD + dd)) * TT + t] = f2bf(v);
          }
        } else {
          ((float*)Cp)[(size_t)gm * N + gn] = v;
        }
      }
    }
}

// ---------------- Flash attention (causal), D=64, 128-row q-tiles ----------------
// 256 thr = 4 waves; wave w owns 32 q rows (two 16-row subtiles i=0,1) ->
// K/V fragments read once per wave feed 2x the MFMAs (LDS-throughput fix).
// Grid (16,32): block x handles q-tile qt=15-x (longest first; 2 blocks/CU).
// Static softmax (scores bounded; no running max), Q pre-scaled by GEMM1.
// Double-buffered kt/vt, ONE barrier/iter; l via ones-B-frag built in regs.
__global__ __launch_bounds__(256) void attn128(
    unsigned short* __restrict__ QK, const unsigned short* __restrict__ Vt)
{
  __shared__ __align__(16) unsigned short kt[2][64 * 72];   // [key][d]
  __shared__ __align__(16) unsigned short vt[2][64 * 72];   // [d][key]
  __shared__ __align__(16) unsigned short pt[4][32 * 72];   // per-wave P (32 q-rows)
  const int qt = 15 - blockIdx.x, bh = blockIdx.y;
  const int b = bh >> 4, h = bh & 15;
  const int tid = threadIdx.x, w = tid >> 6, l = tid & 63, ln = l & 15, quad = l >> 4;
  unsigned short*       Qp = QK + (size_t)b * TT * 2048 + h * DD;
  const unsigned short* Kp = QK + (size_t)b * TT * 2048 + CC + h * DD;
  const unsigned short* Vh = Vt + (size_t)bh * DD * TT;
  const int si = tid >> 3, so = (tid & 7) * 8;              // 256 thr: 2 stores/buf

  // ones B-fragment in registers: row 64+ln of the old ones-block = 1.0 iff ln==0
  bf16x8 blf;
#pragma unroll
  for (int e = 0; e < 8; ++e)
    ((unsigned short*)&blf)[e] = (ln == 0) ? (unsigned short)0x3F80 : (unsigned short)0;

  const int wfirst = qt * 128 + w * 32;                     // wave's first q row
  bf16x8 qf[2][2];
#pragma unroll
  for (int i = 0; i < 2; ++i) {
    const int qrow = wfirst + i * 16 + ln;
    qf[i][0] = *(const bf16x8*)&Qp[(size_t)qrow * 2048 + quad * 8];
    qf[i][1] = *(const bf16x8*)&Qp[(size_t)qrow * 2048 + 32 + quad * 8];
  }

  f32x4 oacc[4][2] = {};
  f32x4 lacc[2] = {};
  const int wlast = wfirst + 31;
  const int kbmax = 2 * qt + 1;

  // stage kb=0 into buffer 0
  *(short8*)&kt[0][si * 72 + so]        = *(const short8*)&Kp[(size_t)si * 2048 + so];
  *(short8*)&kt[0][(si + 32) * 72 + so] = *(const short8*)&Kp[(size_t)(si + 32) * 2048 + so];
  *(short8*)&vt[0][si * 72 + so]        = *(const short8*)&Vh[(size_t)si * TT + so];
  *(short8*)&vt[0][(si + 32) * 72 + so] = *(const short8*)&Vh[(size_t)(si + 32) * TT + so];
  __syncthreads();

  for (int kb = 0; kb <= kbmax; ++kb) {
    const int cur = kb & 1;
    short8 pk0, pk1, pv0, pv1;
    if (kb < kbmax) {                                       // prefetch kb+1
      pk0 = *(const short8*)&Kp[(size_t)((kb + 1) * 64 + si) * 2048 + so];
      pk1 = *(const short8*)&Kp[(size_t)((kb + 1) * 64 + si + 32) * 2048 + so];
      pv0 = *(const short8*)&Vh[(size_t)si * TT + (kb + 1) * 64 + so];
      pv1 = *(const short8*)&Vh[(size_t)(si + 32) * TT + (kb + 1) * 64 + so];
    }
    if (kb * 64 <= wlast) {                                 // wave-uniform active
      f32x4 sacc[2][4] = {};
#pragma unroll
      for (int n = 0; n < 4; n++) {                         // K frags shared by i=0,1
        bf16x8 bk0 = *(const bf16x8*)&kt[cur][(n * 16 + ln) * 72 + quad * 8];
        bf16x8 bk1 = *(const bf16x8*)&kt[cur][(n * 16 + ln) * 72 + 32 + quad * 8];
#pragma unroll
        for (int i = 0; i < 2; ++i) {
          sacc[i][n] = __builtin_amdgcn_mfma_f32_16x16x32_bf16(qf[i][0], bk0, sacc[i][n], 0, 0, 0);
          sacc[i][n] = __builtin_amdgcn_mfma_f32_16x16x32_bf16(qf[i][1], bk1, sacc[i][n], 0, 0, 0);
        }
      }
      if (kb * 64 + 63 > wfirst) {                          // diagonal: mask
#pragma unroll
        for (int i = 0; i < 2; ++i) {
          const int qgi = wfirst + i * 16 + quad * 4;
#pragma unroll
          for (int n = 0; n < 4; n++) {
            const int keyg = kb * 64 + n * 16 + ln;
#pragma unroll
            for (int g = 0; g < 4; ++g)
              if (keyg > qgi + g) sacc[i][n][g] = NEGBIG;
          }
        }
      }
#pragma unroll
      for (int i = 0; i < 2; ++i)
#pragma unroll
        for (int n = 0; n < 4; n++)
#pragma unroll
          for (int g = 0; g < 4; ++g)
            pt[w][(i * 16 + quad * 4 + g) * 72 + n * 16 + ln] = f2bf_tr(exp2f(sacc[i][n][g]));
      __builtin_amdgcn_wave_barrier();                      // order pt write->read
      bf16x8 pf[2][2];
#pragma unroll
      for (int i = 0; i < 2; ++i) {
        pf[i][0] = *(const bf16x8*)&pt[w][(i * 16 + ln) * 72 + quad * 8];
        pf[i][1] = *(const bf16x8*)&pt[w][(i * 16 + ln) * 72 + 32 + quad * 8];
      }
#pragma unroll
      for (int n = 0; n < 4; n++) {                         // V frags shared by i=0,1
        bf16x8 bv0 = *(const bf16x8*)&vt[cur][(n * 16 + ln) * 72 + quad * 8];
        bf16x8 bv1 = *(const bf16x8*)&vt[cur][(n * 16 + ln) * 72 + 32 + quad * 8];
#pragma unroll
        for (int i = 0; i < 2; ++i) {
          oacc[n][i] = __builtin_amdgcn_mfma_f32_16x16x32_bf16(pf[i][0], bv0, oacc[n][i], 0, 0, 0);
          oacc[n][i] = __builtin_amdgcn_mfma_f32_16x16x32_bf16(pf[i][1], bv1, oacc[n][i], 0, 0, 0);
        }
      }
#pragma unroll
      for (int i = 0; i < 2; ++i) {                         // l via ones B-frag (regs)
        lacc[i] = __builtin_amdgcn_mfma_f32_16x16x32_bf16(pf[i][0], blf, lacc[i], 0, 0, 0);
        lacc[i] = __builtin_amdgcn_mfma_f32_16x16x32_bf16(pf[i][1], blf, lacc[i], 0, 0, 0);
      }
    }
    if (kb < kbmax) {                                       // write NEXT buffer
      *(short8*)&kt[1 - cur][si * 72 + so]        = pk0;
      *(short8*)&kt[1 - cur][(si + 32) * 72 + so] = pk1;
      *(short8*)&vt[1 - cur][si * 72 + so]        = pv0;
      *(short8*)&vt[1 - cur][(si + 32) * 72 + so] = pv1;
    }
    __syncthreads();                                        // one barrier per iter
  }
  // epilogue: l in col 0 (lane quad*16); normalize, overwrite own Q rows
#pragma unroll
  for (int i = 0; i < 2; ++i)
#pragma unroll
    for (int g = 0; g < 4; ++g) {
      const float lv = __shfl(lacc[i][g], l & 48);
      const float inv = 1.0f / lv;
      const int t = wfirst + i * 16 + quad * 4 + g;
#pragma unroll
      for (int n = 0; n < 4; n++)
        Qp[(size_t)t * 2048 + n * 16 + ln] = f2bf(oacc[n][i][g] * inv);
    }
}

extern "C" void kernel_launch(void* const* d_in, const int* in_sizes, int n_in,
                              void* d_out, int out_size, void* d_ws, size_t ws_size,
                              hipStream_t stream)
{
  (void)in_sizes; (void)n_in; (void)out_size; (void)ws_size;
  const float* x     = (const float*)d_in[0];   // [B,T,C] fp32
  const float* Wqkv  = (const float*)d_in[1];   // [C,3C]
  const float* bqkv  = (const float*)d_in[2];   // [3C]
  const float* Wproj = (const float*)d_in[3];   // [C,C]
  const float* bproj = (const float*)d_in[4];   // [C]

  unsigned short* QK     = (unsigned short*)d_ws;            // [4096][2048] bf16, 16 MB
  unsigned short* WqkvT  = QK + (size_t)4096 * 2048;         // [3072][1024] bf16, 6 MB
  unsigned short* WprojT = WqkvT;                            // aliases (after GEMM1)
  unsigned short* Vt = (unsigned short*)d_out;               // scratch in d_out, 8 MB
  unsigned short* xb = Vt + (size_t)32 * 64 * 2048;          // scratch in d_out, 8 MB

  cvt_bf16<<<dim3(4096 * 1024 / 8 / 256), 256, 0, stream>>>(x, xb, 4096 * 1024 / 8);
  transpose_cvt<<<dim3(C3 / 64, CC / 64), 256, 0, stream>>>(Wqkv, WqkvT, CC, C3);
  gemm_bt<0><<<dim3(C3 / 128, 4096 / 128), 256, 0, stream>>>(
      xb, WqkvT, bqkv, QK, Vt, 4096, C3, CC, CC);
  transpose_cvt<<<dim3(CC / 64, CC / 64), 256, 0, stream>>>(Wproj, WprojT, CC, CC);
  attn128<<<dim3(16, 2 * HH), 256, 0, stream>>>(QK, Vt);
  gemm_bt<1><<<dim3(CC / 128, 4096 / 128), 256, 0, stream>>>(
      QK, WprojT, bproj, d_out, nullptr, 4096, CC, CC, 2048);
}

// Round 12
// 223.517 us; speedup vs baseline: 1.0465x; 1.0465x over previous
//
#include <hip/hip_runtime.h>
#include <hip/hip_bf16.h>

typedef __attribute__((ext_vector_type(8))) __bf16 bf16x8;
typedef __attribute__((ext_vector_type(8))) short short8;
typedef __attribute__((ext_vector_type(4))) float f32x4;
typedef __attribute__((ext_vector_type(4))) short sh4;

typedef __attribute__((address_space(1))) void GVoid;
typedef __attribute__((address_space(3))) void LVoid;

#define NEGBIG (-1e30f)
#define SCL 0.18033688011112042f   // 0.125 * log2(e): folded into Q at GEMM1 epilogue

constexpr int TT = 2048, CC = 1024, HH = 16, DD = 64, C3 = 3072;

__device__ __forceinline__ unsigned short f2bf(float f) {   // RNE
  unsigned int i = __float_as_uint(f);
  return (unsigned short)((i + 0x7FFFu + ((i >> 16) & 1u)) >> 16);
}
__device__ __forceinline__ unsigned short f2bf_tr(float f) {  // truncate (P only)
  return (unsigned short)(__float_as_uint(f) >> 16);
}
__device__ __forceinline__ void async16(const void* g, void* l) {
  __builtin_amdgcn_global_load_lds((GVoid*)g, (LVoid*)l, 16, 0, 0);
}

// ---------- pre-pass: fp32 -> bf16 elementwise convert ----------
__global__ __launch_bounds__(256) void cvt_bf16(
    const float* __restrict__ in, unsigned short* __restrict__ out, int n8)
{
  const int i = blockIdx.x * 256 + threadIdx.x;
  if (i >= n8) return;
  const float* p = in + (size_t)i * 8;
  f32x4 a = *(const f32x4*)p, b = *(const f32x4*)(p + 4);
  sh4 r0, r1;
  ((unsigned short*)&r0)[0] = f2bf(a[0]); ((unsigned short*)&r0)[1] = f2bf(a[1]);
  ((unsigned short*)&r0)[2] = f2bf(a[2]); ((unsigned short*)&r0)[3] = f2bf(a[3]);
  ((unsigned short*)&r1)[0] = f2bf(b[0]); ((unsigned short*)&r1)[1] = f2bf(b[1]);
  ((unsigned short*)&r1)[2] = f2bf(b[2]); ((unsigned short*)&r1)[3] = f2bf(b[3]);
  *(sh4*)(out + (size_t)i * 8) = r0;
  *(sh4*)(out + (size_t)i * 8 + 4) = r1;
}

// ---------- pre-pass: transpose + convert: fp32 in[R][Cd] -> bf16 out[Cd][R] ----------
__global__ __launch_bounds__(256) void transpose_cvt(
    const float* __restrict__ in, unsigned short* __restrict__ out, int R, int Cd)
{
  __shared__ __align__(16) unsigned short tile[64 * 72];
  const int r0 = blockIdx.y * 64, c0 = blockIdx.x * 64;
  const int tid = threadIdx.x;
#pragma unroll
  for (int r = 0; r < 2; ++r) {
    const int elem = r * 2048 + tid * 8;
    const int ii = elem >> 6, jj = elem & 63;
    const float* p = in + (size_t)(r0 + ii) * Cd + c0 + jj;
    f32x4 a = *(const f32x4*)p, b = *(const f32x4*)(p + 4);
    short8 v;
    ((unsigned short*)&v)[0] = f2bf(a[0]); ((unsigned short*)&v)[1] = f2bf(a[1]);
    ((unsigned short*)&v)[2] = f2bf(a[2]); ((unsigned short*)&v)[3] = f2bf(a[3]);
    ((unsigned short*)&v)[4] = f2bf(b[0]); ((unsigned short*)&v)[5] = f2bf(b[1]);
    ((unsigned short*)&v)[6] = f2bf(b[2]); ((unsigned short*)&v)[7] = f2bf(b[3]);
    *(short8*)&tile[ii * 72 + jj] = v;
  }
  __syncthreads();
#pragma unroll
  for (int r = 0; r < 2; ++r) {
    const int elem = r * 2048 + tid * 8;
    const int jj = elem >> 6, ii0 = elem & 63;
    short8 v;
#pragma unroll
    for (int e = 0; e < 8; ++e) ((unsigned short*)&v)[e] = tile[(ii0 + e) * 72 + jj];
    *(short8*)&out[(size_t)(c0 + jj) * R + r0 + ii0] = v;
  }
}

// ---------------- GEMM (m97 structure, unchanged) ----------------
template <int MODE>
__global__ __launch_bounds__(256) void gemm_bt(
    const unsigned short* __restrict__ A,
    const unsigned short* __restrict__ Bt,
    const float* __restrict__ bias,
    void* __restrict__ Cp, unsigned short* __restrict__ Vt,
    int M, int N, int K, int lda)
{
  __shared__ __align__(16) unsigned short sA[128 * 32];
  __shared__ __align__(16) unsigned short sB[128 * 32];
  const int tid = threadIdx.x;
  const int w = tid >> 6, l = tid & 63, ln = l & 15, quad = l >> 4;
  const int wm = w >> 1, wn = w & 1;
  const int m0 = blockIdx.y * 128, n0 = blockIdx.x * 128;
  f32x4 acc[4][4] = {};

  for (int k0 = 0; k0 < K; k0 += 32) {
    __syncthreads();
#pragma unroll
    for (int r = 0; r < 2; ++r) {
      const int elem = r * 2048 + tid * 8;
      const int ar = elem >> 5, ac = elem & 31;
      async16(A  + (size_t)(m0 + ar) * lda + k0 + ac, sA + r * 2048 + w * 512);
      async16(Bt + (size_t)(n0 + ar) * K   + k0 + ac, sB + r * 2048 + w * 512);
    }
    __syncthreads();

    bf16x8 af[4], bfr[4];
#pragma unroll
    for (int i = 0; i < 4; i++)
      af[i] = *(const bf16x8*)&sA[(wm * 64 + i * 16 + ln) * 32 + quad * 8];
#pragma unroll
    for (int j = 0; j < 4; j++)
      bfr[j] = *(const bf16x8*)&sB[(wn * 64 + j * 16 + ln) * 32 + quad * 8];
#pragma unroll
    for (int i = 0; i < 4; i++)
#pragma unroll
      for (int j = 0; j < 4; j++)
        acc[i][j] = __builtin_amdgcn_mfma_f32_16x16x32_bf16(af[i], bfr[j], acc[i][j], 0, 0, 0);
  }

  float bj[4];
#pragma unroll
  for (int j = 0; j < 4; j++) bj[j] = bias[n0 + wn * 64 + j * 16 + ln];

#pragma unroll
  for (int i = 0; i < 4; i++)
#pragma unroll
    for (int g = 0; g < 4; ++g) {
      const int gm = m0 + wm * 64 + i * 16 + quad * 4 + g;
#pragma unroll
      for (int j = 0; j < 4; j++) {
        const int gn = n0 + wn * 64 + j * 16 + ln;
        float v = acc[i][j][g] + bj[j];
        if (MODE == 0) {
          if (gn < 2048) {
            if (gn < 1024) v *= SCL;       // fold softmax scale into Q
            ((unsigned short*)Cp)[(size_t)gm * 2048 + gn] = f2bf(v);
          } else {
            const int hh = (gn >> 6) & 15, dd = gn & 63;
            const int bb = gm >> 11, t = gm & 2047;
            Vt[((size_t)((bb * HH + hh) * DD + dd)) * TT + t] = f2bf(v);
          }
        } else {
          ((float*)Cp)[(size_t)gm * N + gn] = v;
        }
      }
    }
}

// ---------------- Flash attention (causal), D=64, 64-row q-tiles, paired ----------------
// 128 thr = 2 waves; wave w owns 32 q rows (subtiles i=0,1) -> K/V frags feed 2x
// MFMAs. Grid (16,32): block runs q-tiles {p, 31-p} -> uniform 33 iters. Every
// wave active every iter (64-row tile matches causal granularity); diagonal mask
// only at kb==qt. DOUBLE-buffered kt/vt, one barrier/iter (R9/R10 validated
// skeleton). LDS 46 KB -> 2 resident blocks/CU (6 waves) for barrier overlap.
// Static softmax (Q pre-scaled by GEMM1); l via ones-B-frag in regs.
__global__ __launch_bounds__(128) void attn64p(
    unsigned short* __restrict__ QK, const unsigned short* __restrict__ Vt)
{
  __shared__ __align__(16) unsigned short kt[2][64 * 72];   // [key][d]
  __shared__ __align__(16) unsigned short vt[2][64 * 72];   // [d][key]
  __shared__ __align__(16) unsigned short pt[2][32 * 72];   // per-wave P (32 q-rows)
  const int pair = blockIdx.x, bh = blockIdx.y;
  const int b = bh >> 4, h = bh & 15;
  const int tid = threadIdx.x, w = tid >> 6, l = tid & 63, ln = l & 15, quad = l >> 4;
  unsigned short*       Qp = QK + (size_t)b * TT * 2048 + h * DD;
  const unsigned short* Kp = QK + (size_t)b * TT * 2048 + CC + h * DD;
  const unsigned short* Vh = Vt + (size_t)bh * DD * TT;
  const int si = tid >> 3, so = (tid & 7) * 8;              // si 0..15; 4 row-groups

  // ones B-fragment in registers (l-accumulator column)
  bf16x8 blf;
#pragma unroll
  for (int e = 0; e < 8; ++e)
    ((unsigned short*)&blf)[e] = (ln == 0) ? (unsigned short)0x3F80 : (unsigned short)0;

  for (int ph = 0; ph < 2; ++ph) {
    const int qt = ph ? 31 - pair : pair;
    const int wfirst = qt * 64 + w * 32;                    // wave's first q row
    bf16x8 qf[2][2];
#pragma unroll
    for (int i = 0; i < 2; ++i) {
      const int qrow = wfirst + i * 16 + ln;
      qf[i][0] = *(const bf16x8*)&Qp[(size_t)qrow * 2048 + quad * 8];
      qf[i][1] = *(const bf16x8*)&Qp[(size_t)qrow * 2048 + 32 + quad * 8];
    }
    f32x4 oacc[4][2] = {};
    f32x4 lacc[2] = {};

    // stage kb=0 into buffer 0 (prev phase's reads all precede its final barrier)
#pragma unroll
    for (int r = 0; r < 4; ++r) {
      *(short8*)&kt[0][(si + 16 * r) * 72 + so] = *(const short8*)&Kp[(size_t)(si + 16 * r) * 2048 + so];
      *(short8*)&vt[0][(si + 16 * r) * 72 + so] = *(const short8*)&Vh[(size_t)(si + 16 * r) * TT + so];
    }
    __syncthreads();                                        // buf0 visible

    for (int kb = 0; kb <= qt; ++kb) {
      const int cur = kb & 1;
      short8 pk[4], pv[4];
      if (kb < qt) {                                        // prefetch kb+1 -> regs
#pragma unroll
        for (int r = 0; r < 4; ++r) {
          pk[r] = *(const short8*)&Kp[(size_t)((kb + 1) * 64 + si + 16 * r) * 2048 + so];
          pv[r] = *(const short8*)&Vh[(size_t)(si + 16 * r) * TT + (kb + 1) * 64 + so];
        }
      }

      f32x4 sacc[2][4] = {};
#pragma unroll
      for (int n = 0; n < 4; n++) {                         // K frags shared by i=0,1
        bf16x8 bk0 = *(const bf16x8*)&kt[cur][(n * 16 + ln) * 72 + quad * 8];
        bf16x8 bk1 = *(const bf16x8*)&kt[cur][(n * 16 + ln) * 72 + 32 + quad * 8];
#pragma unroll
        for (int i = 0; i < 2; ++i) {
          sacc[i][n] = __builtin_amdgcn_mfma_f32_16x16x32_bf16(qf[i][0], bk0, sacc[i][n], 0, 0, 0);
          sacc[i][n] = __builtin_amdgcn_mfma_f32_16x16x32_bf16(qf[i][1], bk1, sacc[i][n], 0, 0, 0);
        }
      }
      if (kb == qt) {                                       // diagonal: mask
#pragma unroll
        for (int i = 0; i < 2; ++i) {
          const int qgi = wfirst + i * 16 + quad * 4;
#pragma unroll
          for (int n = 0; n < 4; n++) {
            const int keyg = kb * 64 + n * 16 + ln;
#pragma unroll
            for (int g = 0; g < 4; ++g)
              if (keyg > qgi + g) sacc[i][n][g] = NEGBIG;
          }
        }
      }
#pragma unroll
      for (int i = 0; i < 2; ++i)
#pragma unroll
        for (int n = 0; n < 4; n++)
#pragma unroll
          for (int g = 0; g < 4; ++g)
            pt[w][(i * 16 + quad * 4 + g) * 72 + n * 16 + ln] = f2bf_tr(exp2f(sacc[i][n][g]));
      __builtin_amdgcn_wave_barrier();                      // order pt write->read
      bf16x8 pf[2][2];
#pragma unroll
      for (int i = 0; i < 2; ++i) {
        pf[i][0] = *(const bf16x8*)&pt[w][(i * 16 + ln) * 72 + quad * 8];
        pf[i][1] = *(const bf16x8*)&pt[w][(i * 16 + ln) * 72 + 32 + quad * 8];
      }
#pragma unroll
      for (int n = 0; n < 4; n++) {                         // V frags shared by i=0,1
        bf16x8 bv0 = *(const bf16x8*)&vt[cur][(n * 16 + ln) * 72 + quad * 8];
        bf16x8 bv1 = *(const bf16x8*)&vt[cur][(n * 16 + ln) * 72 + 32 + quad * 8];
#pragma unroll
        for (int i = 0; i < 2; ++i) {
          oacc[n][i] = __builtin_amdgcn_mfma_f32_16x16x32_bf16(pf[i][0], bv0, oacc[n][i], 0, 0, 0);
          oacc[n][i] = __builtin_amdgcn_mfma_f32_16x16x32_bf16(pf[i][1], bv1, oacc[n][i], 0, 0, 0);
        }
      }
#pragma unroll
      for (int i = 0; i < 2; ++i) {                         // l via ones B-frag
        lacc[i] = __builtin_amdgcn_mfma_f32_16x16x32_bf16(pf[i][0], blf, lacc[i], 0, 0, 0);
        lacc[i] = __builtin_amdgcn_mfma_f32_16x16x32_bf16(pf[i][1], blf, lacc[i], 0, 0, 0);
      }

      if (kb < qt) {                                        // write NEXT buffer
#pragma unroll
        for (int r = 0; r < 4; ++r) {
          *(short8*)&kt[1 - cur][(si + 16 * r) * 72 + so] = pk[r];
          *(short8*)&vt[1 - cur][(si + 16 * r) * 72 + so] = pv[r];
        }
      }
      __syncthreads();                                      // one barrier per iter
    }
    // epilogue: l in col 0 (lane quad*16); normalize, overwrite own Q rows
#pragma unroll
    for (int i = 0; i < 2; ++i)
#pragma unroll
      for (int g = 0; g < 4; ++g) {
        const float lv = __shfl(lacc[i][g], l & 48);
        const float inv = 1.0f / lv;
        const int t = qt * 64 + w * 32 + i * 16 + quad * 4 + g;
#pragma unroll
        for (int n = 0; n < 4; n++)
          Qp[(size_t)t * 2048 + n * 16 + ln] = f2bf(oacc[n][i][g] * inv);
      }
  }
}

extern "C" void kernel_launch(void* const* d_in, const int* in_sizes, int n_in,
                              void* d_out, int out_size, void* d_ws, size_t ws_size,
                              hipStream_t stream)
{
  (void)in_sizes; (void)n_in; (void)out_size; (void)ws_size;
  const float* x     = (const float*)d_in[0];   // [B,T,C] fp32
  const float* Wqkv  = (const float*)d_in[1];   // [C,3C]
  const float* bqkv  = (const float*)d_in[2];   // [3C]
  const float* Wproj = (const float*)d_in[3];   // [C,C]
  const float* bproj = (const float*)d_in[4];   // [C]

  unsigned short* QK     = (unsigned short*)d_ws;            // [4096][2048] bf16, 16 MB
  unsigned short* WqkvT  = QK + (size_t)4096 * 2048;         // [3072][1024] bf16, 6 MB
  unsigned short* WprojT = WqkvT;                            // aliases (after GEMM1)
  unsigned short* Vt = (unsigned short*)d_out;               // scratch in d_out, 8 MB
  unsigned short* xb = Vt + (size_t)32 * 64 * 2048;          // scratch in d_out, 8 MB

  cvt_bf16<<<dim3(4096 * 1024 / 8 / 256), 256, 0, stream>>>(x, xb, 4096 * 1024 / 8);
  transpose_cvt<<<dim3(C3 / 64, CC / 64), 256, 0, stream>>>(Wqkv, WqkvT, CC, C3);
  gemm_bt<0><<<dim3(C3 / 128, 4096 / 128), 256, 0, stream>>>(
      xb, WqkvT, bqkv, QK, Vt, 4096, C3, CC, CC);
  transpose_cvt<<<dim3(CC / 64, CC / 64), 256, 0, stream>>>(Wproj, WprojT, CC, CC);
  attn64p<<<dim3(16, 2 * HH), 128, 0, stream>>>(QK, Vt);
  gemm_bt<1><<<dim3(CC / 128, 4096 / 128), 256, 0, stream>>>(
      QK, WprojT, bproj, d_out, nullptr, 4096, CC, CC, 2048);
}